// Round 7
// baseline (1101.407 us; speedup 1.0000x reference)
//
#include <hip/hip_runtime.h>

// B=4, S=2048, D=512, H=8, DK=DV=64
typedef __attribute__((ext_vector_type(8))) short short8;
typedef __attribute__((ext_vector_type(4))) float f32x4;

__device__ __forceinline__ short f2bf(float f) {
  union { float f; unsigned u; } x; x.f = f;
  return (short)((x.u + 0x7FFFu + ((x.u >> 16) & 1u)) >> 16);
}
__device__ __forceinline__ unsigned pk2(float a, float b) {
  return (unsigned)(unsigned short)f2bf(a) | ((unsigned)(unsigned short)f2bf(b) << 16);
}
__device__ __forceinline__ float bfu2f(unsigned lo16) {
  union { unsigned u; float f; } x; x.u = lo16 << 16; return x.f;
}

// Wt[m][n][k] = W_m[k][n], bf16  (3 x 512 x 512)
__global__ __launch_bounds__(256) void prep_wt_k(const float* __restrict__ Wq,
    const float* __restrict__ Wk, const float* __restrict__ Wv,
    short* __restrict__ wt) {
  int idx = blockIdx.x * 256 + threadIdx.x;
  int m = idx >> 18;
  int r = idx & 0x3FFFF;
  int k = r >> 9, n = r & 511;
  const float* W = (m == 0) ? Wq : (m == 1) ? Wk : Wv;
  wt[(m << 18) + (n << 9) + k] = f2bf(W[(k << 9) + n]);
}

// convert q,k,v f32 -> bf16 [3][8192][512]
__global__ __launch_bounds__(256) void xcvt_k(const float* __restrict__ q,
    const float* __restrict__ k_, const float* __restrict__ v,
    short* __restrict__ xb) {
  int i = blockIdx.x * 256 + threadIdx.x;
  int m = i >> 19;
  int r = i & 0x7FFFF;
  const float* X = (m == 0) ? q : (m == 1) ? k_ : v;
  float4 f0 = ((const float4*)X)[2 * r];
  float4 f1 = ((const float4*)X)[2 * r + 1];
  short8 t;
  t[0] = f2bf(f0.x); t[1] = f2bf(f0.y); t[2] = f2bf(f0.z); t[3] = f2bf(f0.w);
  t[4] = f2bf(f1.x); t[5] = f2bf(f1.y); t[6] = f2bf(f1.z); t[7] = f2bf(f1.w);
  *(short8*)(xb + (size_t)i * 8) = t;
}

// X[8192][512] @ Wt[n][k] -> qh [b][h][s][64], kh row-permuted, vt [b][h][dv][s]
template<int BF>
__global__ __launch_bounds__(64) void proj_k(const float* __restrict__ q,
    const float* __restrict__ k_, const float* __restrict__ v,
    const short* __restrict__ xb, const short* __restrict__ wt,
    short* __restrict__ qh, short* __restrict__ kh, short* __restrict__ vt) {
  int bid = blockIdx.x;
  int mat = bid >> 10;
  int t = bid & 1023;
  int tm = t >> 3, tn = t & 7;
  const float* X = (mat == 0) ? q : (mat == 1) ? k_ : v;
  const short* Xb = xb + ((size_t)mat << 22);
  const short* W = wt + ((size_t)mat << 18);
  int lane = threadIdx.x;
  int lr = lane & 15, lg = lane >> 4;
  int m0 = tm << 6, n0 = tn << 6;
  f32x4 acc[4][4];
  #pragma unroll
  for (int i = 0; i < 4; i++)
    #pragma unroll
    for (int j = 0; j < 4; j++) acc[i][j] = (f32x4){0.f, 0.f, 0.f, 0.f};
  for (int k0 = 0; k0 < 512; k0 += 32) {
    short8 a[4], bfr[4];
    #pragma unroll
    for (int i = 0; i < 4; i++) {
      if (BF) {
        a[i] = *(const short8*)(Xb + (size_t)(m0 + 16 * i + lr) * 512 + k0 + 8 * lg);
      } else {
        const float* p = X + (size_t)(m0 + 16 * i + lr) * 512 + k0 + 8 * lg;
        float4 f0 = *(const float4*)p;
        float4 f1 = *(const float4*)(p + 4);
        short8 tt;
        tt[0] = f2bf(f0.x); tt[1] = f2bf(f0.y); tt[2] = f2bf(f0.z); tt[3] = f2bf(f0.w);
        tt[4] = f2bf(f1.x); tt[5] = f2bf(f1.y); tt[6] = f2bf(f1.z); tt[7] = f2bf(f1.w);
        a[i] = tt;
      }
    }
    #pragma unroll
    for (int j = 0; j < 4; j++)
      bfr[j] = *(const short8*)(W + (size_t)(n0 + 16 * j + lr) * 512 + k0 + 8 * lg);
    #pragma unroll
    for (int i = 0; i < 4; i++)
      #pragma unroll
      for (int j = 0; j < 4; j++)
        acc[i][j] = __builtin_amdgcn_mfma_f32_16x16x32_bf16(a[i], bfr[j], acc[i][j], 0, 0, 0);
  }
  #pragma unroll
  for (int i = 0; i < 4; i++)
    #pragma unroll
    for (int j = 0; j < 4; j++)
      #pragma unroll
      for (int r = 0; r < 4; r++) {
        int row = m0 + 16 * i + lg * 4 + r;
        int col = n0 + 16 * j + lr;
        int bb = row >> 11, s = row & 2047;
        int h = col >> 6, d = col & 63;
        short val = f2bf(acc[i][j][r]);
        if (mat == 0) {
          qh[((size_t)((bb * 8 + h) * 2048 + s) << 6) + d] = val;
        } else if (mat == 1) {
          int o = s & 31, aa = o >> 3, b7 = o & 7;
          int loc = (b7 < 4) ? ((aa << 2) | b7) : (16 + ((aa << 2) | (b7 - 4)));
          int sp = (s & ~31) | loc;
          kh[((size_t)((bb * 8 + h) * 2048 + sp) << 6) + d] = val;
        } else {
          vt[((size_t)((bb * 8 + h) * 64 + d) << 11) + s] = val;
        }
      }
}

__device__ __forceinline__ float eterm(float s, float m, float cs, float gl2, float sh2) {
  return __builtin_amdgcn_exp2f(fmaf(s, cs, fmaf(m, gl2, -sh2)));
}

// ======================= ABLATION KERNELS (diagnostic; outputs overwritten) ==

// pure write, identical burst pattern to attn_k's flush (512 MB total)
__global__ __launch_bounds__(512) void abl_write_k(const float* __restrict__ gp,
    float* __restrict__ attn_out) {
  int bid = blockIdx.x;
  int bb = bid >> 7;
  int q0 = (bid & 127) << 4;
  int w = threadIdx.x >> 6;
  int lane = threadIdx.x & 63;
  int bh = bb * 8 + w;
  float* Ab = attn_out + (size_t)bh * (2048 * 2048);
  float g = gp[0];
  f32x4 v = (f32x4){g + lane, g, g - lane, 0.5f * g};
  for (int kc = 0; kc < 2048; kc += 256) {
    #pragma unroll
    for (int r = 0; r < 16; ++r)
      *(f32x4*)(Ab + (size_t)(q0 + r) * 2048 + kc + (lane << 2)) = v;
  }
}

// same but nontemporal (L2-bypass hint)
__global__ __launch_bounds__(512) void abl_write_nt_k(const float* __restrict__ gp,
    float* __restrict__ attn_out) {
  int bid = blockIdx.x;
  int bb = bid >> 7;
  int q0 = (bid & 127) << 4;
  int w = threadIdx.x >> 6;
  int lane = threadIdx.x & 63;
  int bh = bb * 8 + w;
  float* Ab = attn_out + (size_t)bh * (2048 * 2048);
  float g = gp[0];
  f32x4 v = (f32x4){g + lane, g, g - lane, 0.5f * g};
  for (int kc = 0; kc < 2048; kc += 256) {
    #pragma unroll
    for (int r = 0; r < 16; ++r)
      __builtin_nontemporal_store(v,
          (f32x4*)(Ab + (size_t)(q0 + r) * 2048 + kc + (lane << 2)));
  }
}

// attn_k with the attn global write + LDS flush removed (everything else kept)
__global__ __launch_bounds__(512) void abl_core_k(const short* __restrict__ qh,
    const short* __restrict__ kh, const short* __restrict__ vt,
    const float* __restrict__ mask, const float* __restrict__ gamma_p,
    float* __restrict__ out_scratch) {
  __shared__ __align__(16) short P_lds[8][16][256];
  __shared__ __align__(16) float M_lds[16][256];
  int bid = blockIdx.x;
  int bb = bid >> 7;
  int q0 = (bid & 127) << 4;
  int w = threadIdx.x >> 6;
  int lane = threadIdx.x & 63;
  int lr = lane & 15, lg = lane >> 4;
  int bh = bb * 8 + w;
  const short* Kb = kh + (size_t)bh * (2048 * 64);
  const short* Qb = qh + (size_t)bh * (2048 * 64);
  const short* Vb = vt + (size_t)bh * (64 * 2048);
  const float* Mb = mask + (size_t)bb * (2048 * 2048);
  const float LOG2E = 1.4426950408889634f;
  float gamma = gamma_p[0];
  float shift = fmaxf(gamma, 0.f) + 16.0f;
  float cs = 0.125f * LOG2E;
  float gl2 = gamma * LOG2E;
  float sh2 = shift * LOG2E;
  int srow = threadIdx.x >> 5;
  int sc8 = threadIdx.x & 31;
  const float* msrc = Mb + (size_t)(q0 + srow) * 2048 + (sc8 << 3);
  float* mdst = &M_lds[srow][((sc8 ^ (srow & 7)) << 3)];
  short8 qf0 = *(const short8*)(Qb + (size_t)(q0 + lr) * 64 + 8 * lg);
  short8 qf1 = *(const short8*)(Qb + (size_t)(q0 + lr) * 64 + 32 + 8 * lg);
  const float* mrd = &M_lds[lr][0];
  int sw = lr & 7;

  float lsum = 0.f;
  for (int kc = 0; kc < 2048; kc += 256) {
    float4 mg0 = *(const float4*)(msrc + kc);
    float4 mg1 = *(const float4*)(msrc + kc + 4);
    *(float4*)mdst = mg0;
    *(float4*)(mdst + 4) = mg1;
    __syncthreads();
    #pragma unroll
    for (int sub = 0; sub < 4; ++sub) {
      int c0 = sub << 6;
      const short* kp = Kb + (size_t)(kc + c0 + lr) * 64 + (lg << 3);
      short8 kf00 = *(const short8*)(kp);
      short8 kf01 = *(const short8*)(kp + 32);
      short8 kf10 = *(const short8*)(kp + 16 * 64);
      short8 kf11 = *(const short8*)(kp + 16 * 64 + 32);
      short8 kg00 = *(const short8*)(kp + 32 * 64);
      short8 kg01 = *(const short8*)(kp + 32 * 64 + 32);
      short8 kg10 = *(const short8*)(kp + 48 * 64);
      short8 kg11 = *(const short8*)(kp + 48 * 64 + 32);
      f32x4 s0 = (f32x4){0.f, 0.f, 0.f, 0.f};
      s0 = __builtin_amdgcn_mfma_f32_16x16x32_bf16(kf00, qf0, s0, 0, 0, 0);
      s0 = __builtin_amdgcn_mfma_f32_16x16x32_bf16(kf01, qf1, s0, 0, 0, 0);
      f32x4 s1 = (f32x4){0.f, 0.f, 0.f, 0.f};
      s1 = __builtin_amdgcn_mfma_f32_16x16x32_bf16(kf10, qf0, s1, 0, 0, 0);
      s1 = __builtin_amdgcn_mfma_f32_16x16x32_bf16(kf11, qf1, s1, 0, 0, 0);
      f32x4 t0 = (f32x4){0.f, 0.f, 0.f, 0.f};
      t0 = __builtin_amdgcn_mfma_f32_16x16x32_bf16(kg00, qf0, t0, 0, 0, 0);
      t0 = __builtin_amdgcn_mfma_f32_16x16x32_bf16(kg01, qf1, t0, 0, 0, 0);
      f32x4 t1 = (f32x4){0.f, 0.f, 0.f, 0.f};
      t1 = __builtin_amdgcn_mfma_f32_16x16x32_bf16(kg10, qf0, t1, 0, 0, 0);
      t1 = __builtin_amdgcn_mfma_f32_16x16x32_bf16(kg11, qf1, t1, 0, 0, 0);
      int u0 = (((c0 >> 3) + lg) ^ sw) << 3;
      int u1 = (((c0 >> 3) + 4 + lg) ^ sw) << 3;
      float4 ca0 = *(const float4*)(mrd + u0);
      float4 ca1 = *(const float4*)(mrd + u0 + 4);
      float4 cb0 = *(const float4*)(mrd + u1);
      float4 cb1 = *(const float4*)(mrd + u1 + 4);
      lsum += eterm(s0[0], ca0.x, cs, gl2, sh2);
      lsum += eterm(s0[1], ca0.y, cs, gl2, sh2);
      lsum += eterm(s0[2], ca0.z, cs, gl2, sh2);
      lsum += eterm(s0[3], ca0.w, cs, gl2, sh2);
      lsum += eterm(s1[0], ca1.x, cs, gl2, sh2);
      lsum += eterm(s1[1], ca1.y, cs, gl2, sh2);
      lsum += eterm(s1[2], ca1.z, cs, gl2, sh2);
      lsum += eterm(s1[3], ca1.w, cs, gl2, sh2);
      lsum += eterm(t0[0], cb0.x, cs, gl2, sh2);
      lsum += eterm(t0[1], cb0.y, cs, gl2, sh2);
      lsum += eterm(t0[2], cb0.z, cs, gl2, sh2);
      lsum += eterm(t0[3], cb0.w, cs, gl2, sh2);
      lsum += eterm(t1[0], cb1.x, cs, gl2, sh2);
      lsum += eterm(t1[1], cb1.y, cs, gl2, sh2);
      lsum += eterm(t1[2], cb1.z, cs, gl2, sh2);
      lsum += eterm(t1[3], cb1.w, cs, gl2, sh2);
    }
    __syncthreads();
  }
  lsum += __shfl_xor(lsum, 16);
  lsum += __shfl_xor(lsum, 32);
  float inv = 1.0f / lsum;

  f32x4 oacc[4];
  #pragma unroll
  for (int j = 0; j < 4; j++) oacc[j] = (f32x4){0.f, 0.f, 0.f, 0.f};

  for (int kc = 0; kc < 2048; kc += 256) {
    float4 mg0 = *(const float4*)(msrc + kc);
    float4 mg1 = *(const float4*)(msrc + kc + 4);
    *(float4*)mdst = mg0;
    *(float4*)(mdst + 4) = mg1;
    __syncthreads();
    #pragma unroll
    for (int sub = 0; sub < 4; ++sub) {
      int c0 = sub << 6;
      const short* kp = Kb + (size_t)(kc + c0 + lr) * 64 + (lg << 3);
      short8 kf00 = *(const short8*)(kp);
      short8 kf01 = *(const short8*)(kp + 32);
      short8 kf10 = *(const short8*)(kp + 16 * 64);
      short8 kf11 = *(const short8*)(kp + 16 * 64 + 32);
      short8 kg00 = *(const short8*)(kp + 32 * 64);
      short8 kg01 = *(const short8*)(kp + 32 * 64 + 32);
      short8 kg10 = *(const short8*)(kp + 48 * 64);
      short8 kg11 = *(const short8*)(kp + 48 * 64 + 32);
      int u0 = (((c0 >> 3) + lg) ^ sw) << 3;
      int u1 = (((c0 >> 3) + 4 + lg) ^ sw) << 3;
      float4 ca0 = *(const float4*)(mrd + u0);
      float4 ca1 = *(const float4*)(mrd + u0 + 4);
      float4 cb0 = *(const float4*)(mrd + u1);
      float4 cb1 = *(const float4*)(mrd + u1 + 4);
      const short* vp0 = Vb + (size_t)lr * 2048 + kc + c0 + (lg << 3);
      short8 vf0 = *(const short8*)(vp0);
      short8 vf1 = *(const short8*)(vp0 + 16 * 2048);
      short8 vf2 = *(const short8*)(vp0 + 32 * 2048);
      short8 vf3 = *(const short8*)(vp0 + 48 * 2048);
      f32x4 s0 = (f32x4){0.f, 0.f, 0.f, 0.f};
      s0 = __builtin_amdgcn_mfma_f32_16x16x32_bf16(kf00, qf0, s0, 0, 0, 0);
      s0 = __builtin_amdgcn_mfma_f32_16x16x32_bf16(kf01, qf1, s0, 0, 0, 0);
      f32x4 s1 = (f32x4){0.f, 0.f, 0.f, 0.f};
      s1 = __builtin_amdgcn_mfma_f32_16x16x32_bf16(kf10, qf0, s1, 0, 0, 0);
      s1 = __builtin_amdgcn_mfma_f32_16x16x32_bf16(kf11, qf1, s1, 0, 0, 0);
      float p00 = eterm(s0[0], ca0.x, cs, gl2, sh2) * inv;
      float p01 = eterm(s0[1], ca0.y, cs, gl2, sh2) * inv;
      float p02 = eterm(s0[2], ca0.z, cs, gl2, sh2) * inv;
      float p03 = eterm(s0[3], ca0.w, cs, gl2, sh2) * inv;
      float p10 = eterm(s1[0], ca1.x, cs, gl2, sh2) * inv;
      float p11 = eterm(s1[1], ca1.y, cs, gl2, sh2) * inv;
      float p12 = eterm(s1[2], ca1.z, cs, gl2, sh2) * inv;
      float p13 = eterm(s1[3], ca1.w, cs, gl2, sh2) * inv;
      union { unsigned u[4]; short8 s8; uint4 q4; } pu;
      pu.u[0] = pk2(p00, p01);
      pu.u[1] = pk2(p02, p03);
      pu.u[2] = pk2(p10, p11);
      pu.u[3] = pk2(p12, p13);
      { int c16 = (c0 >> 3) + lg;
        *(uint4*)&P_lds[w][lr][(c16 ^ sw) << 3] = pu.q4; }
      oacc[0] = __builtin_amdgcn_mfma_f32_16x16x32_bf16(pu.s8, vf0, oacc[0], 0, 0, 0);
      oacc[1] = __builtin_amdgcn_mfma_f32_16x16x32_bf16(pu.s8, vf1, oacc[1], 0, 0, 0);
      oacc[2] = __builtin_amdgcn_mfma_f32_16x16x32_bf16(pu.s8, vf2, oacc[2], 0, 0, 0);
      oacc[3] = __builtin_amdgcn_mfma_f32_16x16x32_bf16(pu.s8, vf3, oacc[3], 0, 0, 0);
      const short* vp1 = vp0 + 32;
      short8 ve0 = *(const short8*)(vp1);
      short8 ve1 = *(const short8*)(vp1 + 16 * 2048);
      short8 ve2 = *(const short8*)(vp1 + 32 * 2048);
      short8 ve3 = *(const short8*)(vp1 + 48 * 2048);
      f32x4 t0 = (f32x4){0.f, 0.f, 0.f, 0.f};
      t0 = __builtin_amdgcn_mfma_f32_16x16x32_bf16(kg00, qf0, t0, 0, 0, 0);
      t0 = __builtin_amdgcn_mfma_f32_16x16x32_bf16(kg01, qf1, t0, 0, 0, 0);
      f32x4 t1 = (f32x4){0.f, 0.f, 0.f, 0.f};
      t1 = __builtin_amdgcn_mfma_f32_16x16x32_bf16(kg10, qf0, t1, 0, 0, 0);
      t1 = __builtin_amdgcn_mfma_f32_16x16x32_bf16(kg11, qf1, t1, 0, 0, 0);
      float q00 = eterm(t0[0], cb0.x, cs, gl2, sh2) * inv;
      float q01 = eterm(t0[1], cb0.y, cs, gl2, sh2) * inv;
      float q02 = eterm(t0[2], cb0.z, cs, gl2, sh2) * inv;
      float q03 = eterm(t0[3], cb0.w, cs, gl2, sh2) * inv;
      float q10 = eterm(t1[0], cb1.x, cs, gl2, sh2) * inv;
      float q11 = eterm(t1[1], cb1.y, cs, gl2, sh2) * inv;
      float q12 = eterm(t1[2], cb1.z, cs, gl2, sh2) * inv;
      float q13 = eterm(t1[3], cb1.w, cs, gl2, sh2) * inv;
      union { unsigned u[4]; short8 s8; uint4 q4; } qu;
      qu.u[0] = pk2(q00, q01);
      qu.u[1] = pk2(q02, q03);
      qu.u[2] = pk2(q10, q11);
      qu.u[3] = pk2(q12, q13);
      { int c16 = (c0 >> 3) + 4 + lg;
        *(uint4*)&P_lds[w][lr][(c16 ^ sw) << 3] = qu.q4; }
      oacc[0] = __builtin_amdgcn_mfma_f32_16x16x32_bf16(qu.s8, ve0, oacc[0], 0, 0, 0);
      oacc[1] = __builtin_amdgcn_mfma_f32_16x16x32_bf16(qu.s8, ve1, oacc[1], 0, 0, 0);
      oacc[2] = __builtin_amdgcn_mfma_f32_16x16x32_bf16(qu.s8, ve2, oacc[2], 0, 0, 0);
      oacc[3] = __builtin_amdgcn_mfma_f32_16x16x32_bf16(qu.s8, ve3, oacc[3], 0, 0, 0);
    }
    __syncthreads();
  }

  int h = w;
  #pragma unroll
  for (int j = 0; j < 4; j++)
    #pragma unroll
    for (int r = 0; r < 4; r++) {
      int qq = q0 + (lg << 2) + r;
      out_scratch[((size_t)(bb * 2048) + qq) * 512 + (h << 6) + (j << 4) + lr] = oacc[j][r];
    }
}

// ======================= REAL KERNEL (unchanged from R5) =====================
__global__ __launch_bounds__(512) void attn_k(const short* __restrict__ qh,
    const short* __restrict__ kh, const short* __restrict__ vt,
    const float* __restrict__ mask, const float* __restrict__ gamma_p,
    float* __restrict__ out, float* __restrict__ attn_out) {
  __shared__ __align__(16) short P_lds[8][16][256];
  __shared__ __align__(16) float M_lds[16][256];

  int bid = blockIdx.x;
  int bb = bid >> 7;
  int q0 = (bid & 127) << 4;
  int w = threadIdx.x >> 6;
  int lane = threadIdx.x & 63;
  int lr = lane & 15, lg = lane >> 4;
  int bh = bb * 8 + w;
  const short* Kb = kh + (size_t)bh * (2048 * 64);
  const short* Qb = qh + (size_t)bh * (2048 * 64);
  const short* Vb = vt + (size_t)bh * (64 * 2048);
  const float* Mb = mask + (size_t)bb * (2048 * 2048);
  float* Ab = attn_out + (size_t)bh * (2048 * 2048);
  const float LOG2E = 1.4426950408889634f;
  float gamma = gamma_p[0];
  float shift = fmaxf(gamma, 0.f) + 16.0f;
  float cs = 0.125f * LOG2E;
  float gl2 = gamma * LOG2E;
  float sh2 = shift * LOG2E;

  int srow = threadIdx.x >> 5;
  int sc8 = threadIdx.x & 31;
  const float* msrc = Mb + (size_t)(q0 + srow) * 2048 + (sc8 << 3);
  float* mdst = &M_lds[srow][((sc8 ^ (srow & 7)) << 3)];

  short8 qf0 = *(const short8*)(Qb + (size_t)(q0 + lr) * 64 + 8 * lg);
  short8 qf1 = *(const short8*)(Qb + (size_t)(q0 + lr) * 64 + 32 + 8 * lg);
  const float* mrd = &M_lds[lr][0];
  int sw = lr & 7;

  float lsum = 0.f;
  for (int kc = 0; kc < 2048; kc += 256) {
    float4 mg0 = *(const float4*)(msrc + kc);
    float4 mg1 = *(const float4*)(msrc + kc + 4);
    *(float4*)mdst = mg0;
    *(float4*)(mdst + 4) = mg1;
    __syncthreads();
    #pragma unroll
    for (int sub = 0; sub < 4; ++sub) {
      int c0 = sub << 6;
      const short* kp = Kb + (size_t)(kc + c0 + lr) * 64 + (lg << 3);
      short8 kf00 = *(const short8*)(kp);
      short8 kf01 = *(const short8*)(kp + 32);
      short8 kf10 = *(const short8*)(kp + 16 * 64);
      short8 kf11 = *(const short8*)(kp + 16 * 64 + 32);
      short8 kg00 = *(const short8*)(kp + 32 * 64);
      short8 kg01 = *(const short8*)(kp + 32 * 64 + 32);
      short8 kg10 = *(const short8*)(kp + 48 * 64);
      short8 kg11 = *(const short8*)(kp + 48 * 64 + 32);
      f32x4 s0 = (f32x4){0.f, 0.f, 0.f, 0.f};
      s0 = __builtin_amdgcn_mfma_f32_16x16x32_bf16(kf00, qf0, s0, 0, 0, 0);
      s0 = __builtin_amdgcn_mfma_f32_16x16x32_bf16(kf01, qf1, s0, 0, 0, 0);
      f32x4 s1 = (f32x4){0.f, 0.f, 0.f, 0.f};
      s1 = __builtin_amdgcn_mfma_f32_16x16x32_bf16(kf10, qf0, s1, 0, 0, 0);
      s1 = __builtin_amdgcn_mfma_f32_16x16x32_bf16(kf11, qf1, s1, 0, 0, 0);
      f32x4 t0 = (f32x4){0.f, 0.f, 0.f, 0.f};
      t0 = __builtin_amdgcn_mfma_f32_16x16x32_bf16(kg00, qf0, t0, 0, 0, 0);
      t0 = __builtin_amdgcn_mfma_f32_16x16x32_bf16(kg01, qf1, t0, 0, 0, 0);
      f32x4 t1 = (f32x4){0.f, 0.f, 0.f, 0.f};
      t1 = __builtin_amdgcn_mfma_f32_16x16x32_bf16(kg10, qf0, t1, 0, 0, 0);
      t1 = __builtin_amdgcn_mfma_f32_16x16x32_bf16(kg11, qf1, t1, 0, 0, 0);
      int u0 = (((c0 >> 3) + lg) ^ sw) << 3;
      int u1 = (((c0 >> 3) + 4 + lg) ^ sw) << 3;
      float4 ca0 = *(const float4*)(mrd + u0);
      float4 ca1 = *(const float4*)(mrd + u0 + 4);
      float4 cb0 = *(const float4*)(mrd + u1);
      float4 cb1 = *(const float4*)(mrd + u1 + 4);
      lsum += eterm(s0[0], ca0.x, cs, gl2, sh2);
      lsum += eterm(s0[1], ca0.y, cs, gl2, sh2);
      lsum += eterm(s0[2], ca0.z, cs, gl2, sh2);
      lsum += eterm(s0[3], ca0.w, cs, gl2, sh2);
      lsum += eterm(s1[0], ca1.x, cs, gl2, sh2);
      lsum += eterm(s1[1], ca1.y, cs, gl2, sh2);
      lsum += eterm(s1[2], ca1.z, cs, gl2, sh2);
      lsum += eterm(s1[3], ca1.w, cs, gl2, sh2);
      lsum += eterm(t0[0], cb0.x, cs, gl2, sh2);
      lsum += eterm(t0[1], cb0.y, cs, gl2, sh2);
      lsum += eterm(t0[2], cb0.z, cs, gl2, sh2);
      lsum += eterm(t0[3], cb0.w, cs, gl2, sh2);
      lsum += eterm(t1[0], cb1.x, cs, gl2, sh2);
      lsum += eterm(t1[1], cb1.y, cs, gl2, sh2);
      lsum += eterm(t1[2], cb1.z, cs, gl2, sh2);
      lsum += eterm(t1[3], cb1.w, cs, gl2, sh2);
    }
    __syncthreads();
  }
  lsum += __shfl_xor(lsum, 16);
  lsum += __shfl_xor(lsum, 32);
  float inv = 1.0f / lsum;

  f32x4 oacc[4];
  #pragma unroll
  for (int j = 0; j < 4; j++) oacc[j] = (f32x4){0.f, 0.f, 0.f, 0.f};

  for (int kc = 0; kc < 2048; kc += 256) {
    float4 mg0 = *(const float4*)(msrc + kc);
    float4 mg1 = *(const float4*)(msrc + kc + 4);
    *(float4*)mdst = mg0;
    *(float4*)(mdst + 4) = mg1;
    __syncthreads();
    #pragma unroll
    for (int sub = 0; sub < 4; ++sub) {
      int c0 = sub << 6;
      const short* kp = Kb + (size_t)(kc + c0 + lr) * 64 + (lg << 3);
      short8 kf00 = *(const short8*)(kp);
      short8 kf01 = *(const short8*)(kp + 32);
      short8 kf10 = *(const short8*)(kp + 16 * 64);
      short8 kf11 = *(const short8*)(kp + 16 * 64 + 32);
      short8 kg00 = *(const short8*)(kp + 32 * 64);
      short8 kg01 = *(const short8*)(kp + 32 * 64 + 32);
      short8 kg10 = *(const short8*)(kp + 48 * 64);
      short8 kg11 = *(const short8*)(kp + 48 * 64 + 32);
      int u0 = (((c0 >> 3) + lg) ^ sw) << 3;
      int u1 = (((c0 >> 3) + 4 + lg) ^ sw) << 3;
      float4 ca0 = *(const float4*)(mrd + u0);
      float4 ca1 = *(const float4*)(mrd + u0 + 4);
      float4 cb0 = *(const float4*)(mrd + u1);
      float4 cb1 = *(const float4*)(mrd + u1 + 4);

      const short* vp0 = Vb + (size_t)lr * 2048 + kc + c0 + (lg << 3);
      short8 vf0 = *(const short8*)(vp0);
      short8 vf1 = *(const short8*)(vp0 + 16 * 2048);
      short8 vf2 = *(const short8*)(vp0 + 32 * 2048);
      short8 vf3 = *(const short8*)(vp0 + 48 * 2048);
      f32x4 s0 = (f32x4){0.f, 0.f, 0.f, 0.f};
      s0 = __builtin_amdgcn_mfma_f32_16x16x32_bf16(kf00, qf0, s0, 0, 0, 0);
      s0 = __builtin_amdgcn_mfma_f32_16x16x32_bf16(kf01, qf1, s0, 0, 0, 0);
      f32x4 s1 = (f32x4){0.f, 0.f, 0.f, 0.f};
      s1 = __builtin_amdgcn_mfma_f32_16x16x32_bf16(kf10, qf0, s1, 0, 0, 0);
      s1 = __builtin_amdgcn_mfma_f32_16x16x32_bf16(kf11, qf1, s1, 0, 0, 0);
      float p00 = eterm(s0[0], ca0.x, cs, gl2, sh2) * inv;
      float p01 = eterm(s0[1], ca0.y, cs, gl2, sh2) * inv;
      float p02 = eterm(s0[2], ca0.z, cs, gl2, sh2) * inv;
      float p03 = eterm(s0[3], ca0.w, cs, gl2, sh2) * inv;
      float p10 = eterm(s1[0], ca1.x, cs, gl2, sh2) * inv;
      float p11 = eterm(s1[1], ca1.y, cs, gl2, sh2) * inv;
      float p12 = eterm(s1[2], ca1.z, cs, gl2, sh2) * inv;
      float p13 = eterm(s1[3], ca1.w, cs, gl2, sh2) * inv;
      union { unsigned u[4]; short8 s8; uint4 q4; } pu;
      pu.u[0] = pk2(p00, p01);
      pu.u[1] = pk2(p02, p03);
      pu.u[2] = pk2(p10, p11);
      pu.u[3] = pk2(p12, p13);
      {
        int c16 = (c0 >> 3) + lg;
        *(uint4*)&P_lds[w][lr][(c16 ^ sw) << 3] = pu.q4;
      }
      oacc[0] = __builtin_amdgcn_mfma_f32_16x16x32_bf16(pu.s8, vf0, oacc[0], 0, 0, 0);
      oacc[1] = __builtin_amdgcn_mfma_f32_16x16x32_bf16(pu.s8, vf1, oacc[1], 0, 0, 0);
      oacc[2] = __builtin_amdgcn_mfma_f32_16x16x32_bf16(pu.s8, vf2, oacc[2], 0, 0, 0);
      oacc[3] = __builtin_amdgcn_mfma_f32_16x16x32_bf16(pu.s8, vf3, oacc[3], 0, 0, 0);

      const short* vp1 = vp0 + 32;
      short8 ve0 = *(const short8*)(vp1);
      short8 ve1 = *(const short8*)(vp1 + 16 * 2048);
      short8 ve2 = *(const short8*)(vp1 + 32 * 2048);
      short8 ve3 = *(const short8*)(vp1 + 48 * 2048);
      f32x4 t0 = (f32x4){0.f, 0.f, 0.f, 0.f};
      t0 = __builtin_amdgcn_mfma_f32_16x16x32_bf16(kg00, qf0, t0, 0, 0, 0);
      t0 = __builtin_amdgcn_mfma_f32_16x16x32_bf16(kg01, qf1, t0, 0, 0, 0);
      f32x4 t1 = (f32x4){0.f, 0.f, 0.f, 0.f};
      t1 = __builtin_amdgcn_mfma_f32_16x16x32_bf16(kg10, qf0, t1, 0, 0, 0);
      t1 = __builtin_amdgcn_mfma_f32_16x16x32_bf16(kg11, qf1, t1, 0, 0, 0);
      float q00 = eterm(t0[0], cb0.x, cs, gl2, sh2) * inv;
      float q01 = eterm(t0[1], cb0.y, cs, gl2, sh2) * inv;
      float q02 = eterm(t0[2], cb0.z, cs, gl2, sh2) * inv;
      float q03 = eterm(t0[3], cb0.w, cs, gl2, sh2) * inv;
      float q10 = eterm(t1[0], cb1.x, cs, gl2, sh2) * inv;
      float q11 = eterm(t1[1], cb1.y, cs, gl2, sh2) * inv;
      float q12 = eterm(t1[2], cb1.z, cs, gl2, sh2) * inv;
      float q13 = eterm(t1[3], cb1.w, cs, gl2, sh2) * inv;
      union { unsigned u[4]; short8 s8; uint4 q4; } qu;
      qu.u[0] = pk2(q00, q01);
      qu.u[1] = pk2(q02, q03);
      qu.u[2] = pk2(q10, q11);
      qu.u[3] = pk2(q12, q13);
      {
        int c16 = (c0 >> 3) + 4 + lg;
        *(uint4*)&P_lds[w][lr][(c16 ^ sw) << 3] = qu.q4;
      }
      oacc[0] = __builtin_amdgcn_mfma_f32_16x16x32_bf16(qu.s8, ve0, oacc[0], 0, 0, 0);
      oacc[1] = __builtin_amdgcn_mfma_f32_16x16x32_bf16(qu.s8, ve1, oacc[1], 0, 0, 0);
      oacc[2] = __builtin_amdgcn_mfma_f32_16x16x32_bf16(qu.s8, ve2, oacc[2], 0, 0, 0);
      oacc[3] = __builtin_amdgcn_mfma_f32_16x16x32_bf16(qu.s8, ve3, oacc[3], 0, 0, 0);
    }
    asm volatile("s_waitcnt lgkmcnt(0)" ::: "memory");
    __builtin_amdgcn_sched_barrier(0);
    #pragma unroll
    for (int r = 0; r < 16; ++r) {
      const unsigned* pr = (const unsigned*)&P_lds[w][r]
          [(((lane >> 1) ^ (r & 7)) << 3) + ((lane & 1) << 2)];
      uint2 pv = *(const uint2*)pr;
      float4 o;
      o.x = bfu2f(pv.x & 0xFFFFu);
      o.y = bfu2f(pv.x >> 16);
      o.z = bfu2f(pv.y & 0xFFFFu);
      o.w = bfu2f(pv.y >> 16);
      *(float4*)(Ab + (size_t)(q0 + r) * 2048 + kc + (lane << 2)) = o;
    }
    __syncthreads();
  }

  int h = w;
  #pragma unroll
  for (int j = 0; j < 4; j++)
    #pragma unroll
    for (int r = 0; r < 4; r++) {
      int qq = q0 + (lg << 2) + r;
      out[((size_t)(bb * 2048) + qq) * 512 + (h << 6) + (j << 4) + lr] = oacc[j][r];
    }
}

extern "C" void kernel_launch(void* const* d_in, const int* in_sizes, int n_in,
                              void* d_out, int out_size, void* d_ws, size_t ws_size,
                              hipStream_t stream) {
  const float* q    = (const float*)d_in[0];
  const float* k    = (const float*)d_in[1];
  const float* v    = (const float*)d_in[2];
  const float* mask = (const float*)d_in[3];
  const float* Wq   = (const float*)d_in[4];
  const float* Wk   = (const float*)d_in[5];
  const float* Wv   = (const float*)d_in[6];
  const float* gma  = (const float*)d_in[7];
  float* out = (float*)d_out;
  float* attn_out = out + (size_t)4 * 2048 * 512;

  short* wt = (short*)d_ws;                              // 1.5 MB
  short* qh = (short*)((char*)d_ws + (2u << 20));        // 8 MB
  short* kh = qh + (size_t)4 * 8 * 2048 * 64;            // 8 MB (row-permuted)
  short* vt = kh + (size_t)4 * 8 * 2048 * 64;            // 8 MB
  short* xb = vt + (size_t)4 * 8 * 2048 * 64;            // 24 MB (optional)
  bool big_ws = ws_size >= (size_t)(50u << 20);

  hipLaunchKernelGGL(prep_wt_k, dim3(3072), dim3(256), 0, stream, Wq, Wk, Wv, wt);
  if (big_ws) {
    hipLaunchKernelGGL(xcvt_k, dim3(6144), dim3(256), 0, stream, q, k, v, xb);
    hipLaunchKernelGGL(proj_k<1>, dim3(3072), dim3(64), 0, stream, q, k, v, xb, wt, qh, kh, vt);
  } else {
    hipLaunchKernelGGL(proj_k<0>, dim3(3072), dim3(64), 0, stream, q, k, v, xb, wt, qh, kh, vt);
  }

  // ---- diagnostic dispatches (garbage results; fully overwritten below) ----
  hipLaunchKernelGGL(abl_core_k, dim3(512), dim3(512), 0, stream, qh, kh, vt, mask, gma,
                     attn_out);
  hipLaunchKernelGGL(abl_write_k, dim3(512), dim3(512), 0, stream, gma, attn_out);
  hipLaunchKernelGGL(abl_write_nt_k, dim3(512), dim3(512), 0, stream, gma, attn_out);

  // ---- real kernel (overwrites all diagnostic output) ----
  hipLaunchKernelGGL(attn_k, dim3(512), dim3(512), 0, stream, qh, kh, vt, mask, gma,
                     out, attn_out);
}

// Round 8
// 550.006 us; speedup vs baseline: 2.0025x; 2.0025x over previous
//
#include <hip/hip_runtime.h>

// B=4, S=2048, D=512, H=8, DK=DV=64
typedef __attribute__((ext_vector_type(8))) short short8;
typedef __attribute__((ext_vector_type(4))) float f32x4;

__device__ __forceinline__ short f2bf(float f) {
  union { float f; unsigned u; } x; x.f = f;
  return (short)((x.u + 0x7FFFu + ((x.u >> 16) & 1u)) >> 16);
}
__device__ __forceinline__ unsigned pk2(float a, float b) {
  return (unsigned)(unsigned short)f2bf(a) | ((unsigned)(unsigned short)f2bf(b) << 16);
}
__device__ __forceinline__ float bfu2f(unsigned lo16) {
  union { unsigned u; float f; } x; x.u = lo16 << 16; return x.f;
}

// Wt[m][n][k] = W_m[k][n], bf16  (3 x 512 x 512)
__global__ __launch_bounds__(256) void prep_wt_k(const float* __restrict__ Wq,
    const float* __restrict__ Wk, const float* __restrict__ Wv,
    short* __restrict__ wt) {
  int idx = blockIdx.x * 256 + threadIdx.x;
  int m = idx >> 18;
  int r = idx & 0x3FFFF;
  int k = r >> 9, n = r & 511;
  const float* W = (m == 0) ? Wq : (m == 1) ? Wk : Wv;
  wt[(m << 18) + (n << 9) + k] = f2bf(W[(k << 9) + n]);
}

// convert q,k,v f32 -> bf16 [3][8192][512]
__global__ __launch_bounds__(256) void xcvt_k(const float* __restrict__ q,
    const float* __restrict__ k_, const float* __restrict__ v,
    short* __restrict__ xb) {
  int i = blockIdx.x * 256 + threadIdx.x;
  int m = i >> 19;
  int r = i & 0x7FFFF;
  const float* X = (m == 0) ? q : (m == 1) ? k_ : v;
  float4 f0 = ((const float4*)X)[2 * r];
  float4 f1 = ((const float4*)X)[2 * r + 1];
  short8 t;
  t[0] = f2bf(f0.x); t[1] = f2bf(f0.y); t[2] = f2bf(f0.z); t[3] = f2bf(f0.w);
  t[4] = f2bf(f1.x); t[5] = f2bf(f1.y); t[6] = f2bf(f1.z); t[7] = f2bf(f1.w);
  *(short8*)(xb + (size_t)i * 8) = t;
}

// X[8192][512] @ Wt[n][k] -> qh [b][h][s][64], kh row-permuted, vt [b][h][dv][s]
template<int BF>
__global__ __launch_bounds__(64) void proj_k(const float* __restrict__ q,
    const float* __restrict__ k_, const float* __restrict__ v,
    const short* __restrict__ xb, const short* __restrict__ wt,
    short* __restrict__ qh, short* __restrict__ kh, short* __restrict__ vt) {
  int bid = blockIdx.x;
  int mat = bid >> 10;
  int t = bid & 1023;
  int tm = t >> 3, tn = t & 7;
  const float* X = (mat == 0) ? q : (mat == 1) ? k_ : v;
  const short* Xb = xb + ((size_t)mat << 22);
  const short* W = wt + ((size_t)mat << 18);
  int lane = threadIdx.x;
  int lr = lane & 15, lg = lane >> 4;
  int m0 = tm << 6, n0 = tn << 6;
  f32x4 acc[4][4];
  #pragma unroll
  for (int i = 0; i < 4; i++)
    #pragma unroll
    for (int j = 0; j < 4; j++) acc[i][j] = (f32x4){0.f, 0.f, 0.f, 0.f};
  for (int k0 = 0; k0 < 512; k0 += 32) {
    short8 a[4], bfr[4];
    #pragma unroll
    for (int i = 0; i < 4; i++) {
      if (BF) {
        a[i] = *(const short8*)(Xb + (size_t)(m0 + 16 * i + lr) * 512 + k0 + 8 * lg);
      } else {
        const float* p = X + (size_t)(m0 + 16 * i + lr) * 512 + k0 + 8 * lg;
        float4 f0 = *(const float4*)p;
        float4 f1 = *(const float4*)(p + 4);
        short8 tt;
        tt[0] = f2bf(f0.x); tt[1] = f2bf(f0.y); tt[2] = f2bf(f0.z); tt[3] = f2bf(f0.w);
        tt[4] = f2bf(f1.x); tt[5] = f2bf(f1.y); tt[6] = f2bf(f1.z); tt[7] = f2bf(f1.w);
        a[i] = tt;
      }
    }
    #pragma unroll
    for (int j = 0; j < 4; j++)
      bfr[j] = *(const short8*)(W + (size_t)(n0 + 16 * j + lr) * 512 + k0 + 8 * lg);
    #pragma unroll
    for (int i = 0; i < 4; i++)
      #pragma unroll
      for (int j = 0; j < 4; j++)
        acc[i][j] = __builtin_amdgcn_mfma_f32_16x16x32_bf16(a[i], bfr[j], acc[i][j], 0, 0, 0);
  }
  #pragma unroll
  for (int i = 0; i < 4; i++)
    #pragma unroll
    for (int j = 0; j < 4; j++)
      #pragma unroll
      for (int r = 0; r < 4; r++) {
        int row = m0 + 16 * i + lg * 4 + r;
        int col = n0 + 16 * j + lr;
        int bb = row >> 11, s = row & 2047;
        int h = col >> 6, d = col & 63;
        short val = f2bf(acc[i][j][r]);
        if (mat == 0) {
          qh[((size_t)((bb * 8 + h) * 2048 + s) << 6) + d] = val;
        } else if (mat == 1) {
          int o = s & 31, aa = o >> 3, b7 = o & 7;
          int loc = (b7 < 4) ? ((aa << 2) | b7) : (16 + ((aa << 2) | (b7 - 4)));
          int sp = (s & ~31) | loc;
          kh[((size_t)((bb * 8 + h) * 2048 + sp) << 6) + d] = val;
        } else {
          vt[((size_t)((bb * 8 + h) * 64 + d) << 11) + s] = val;
        }
      }
}

__device__ __forceinline__ float eterm(float s, float m, float cs, float gl2, float sh2) {
  return __builtin_amdgcn_exp2f(fmaf(s, cs, fmaf(m, gl2, -sh2)));
}

// Block = (batch, 16 q-rows) x 8 heads (wave = head). Mask staged once in LDS.
// Inner loop: 32-col mini-subs with explicit 1-deep K register prefetch.
__global__ __launch_bounds__(512) void attn_k(const short* __restrict__ qh,
    const short* __restrict__ kh, const short* __restrict__ vt,
    const float* __restrict__ mask, const float* __restrict__ gamma_p,
    float* __restrict__ out, float* __restrict__ attn_out) {
  __shared__ __align__(16) short P_lds[8][16][256];   // 64 KB
  __shared__ __align__(16) float M_lds[16][256];      // 16 KB

  int bid = blockIdx.x;
  int bb = bid >> 7;
  int q0 = (bid & 127) << 4;
  int w = threadIdx.x >> 6;
  int lane = threadIdx.x & 63;
  int lr = lane & 15, lg = lane >> 4;
  int bh = bb * 8 + w;
  const short* Kb = kh + (size_t)bh * (2048 * 64);
  const short* Qb = qh + (size_t)bh * (2048 * 64);
  const short* Vb = vt + (size_t)bh * (64 * 2048);
  const float* Mb = mask + (size_t)bb * (2048 * 2048);
  float* Ab = attn_out + (size_t)bh * (2048 * 2048);
  const float LOG2E = 1.4426950408889634f;
  float gamma = gamma_p[0];
  float shift = fmaxf(gamma, 0.f) + 16.0f;
  float cs = 0.125f * LOG2E;
  float gl2 = gamma * LOG2E;
  float sh2 = shift * LOG2E;

  int srow = threadIdx.x >> 5;
  int sc8 = threadIdx.x & 31;
  const float* msrc = Mb + (size_t)(q0 + srow) * 2048 + (sc8 << 3);
  float* mdst = &M_lds[srow][((sc8 ^ (srow & 7)) << 3)];

  short8 qf0 = *(const short8*)(Qb + (size_t)(q0 + lr) * 64 + 8 * lg);
  short8 qf1 = *(const short8*)(Qb + (size_t)(q0 + lr) * 64 + 32 + 8 * lg);
  const float* mrd = &M_lds[lr][0];
  int sw = lr & 7;

  // ================= pass A: row sums (K prefetched 1 mini ahead) ==========
  float lsum = 0.f;
  {
    const short* kp0 = Kb + (size_t)lr * 64 + (lg << 3);
    short8 kA = *(const short8*)(kp0);
    short8 kB = *(const short8*)(kp0 + 32);
    short8 kC = *(const short8*)(kp0 + 1024);
    short8 kD = *(const short8*)(kp0 + 1024 + 32);
    for (int kc = 0; kc < 2048; kc += 256) {
      float4 mg0 = *(const float4*)(msrc + kc);
      float4 mg1 = *(const float4*)(msrc + kc + 4);
      *(float4*)mdst = mg0;
      *(float4*)(mdst + 4) = mg1;
      __syncthreads();
      #pragma unroll
      for (int mi = 0; mi < 8; ++mi) {
        int cc = mi << 5;
        int cn = (kc + cc + 32) & 2047;
        const short* kpn = Kb + (size_t)(cn + lr) * 64 + (lg << 3);
        short8 nA = *(const short8*)(kpn);
        short8 nB = *(const short8*)(kpn + 32);
        short8 nC = *(const short8*)(kpn + 1024);
        short8 nD = *(const short8*)(kpn + 1024 + 32);
        int u = (((cc >> 3) + lg) ^ sw) << 3;
        float4 ca0 = *(const float4*)(mrd + u);
        float4 ca1 = *(const float4*)(mrd + u + 4);
        f32x4 s0 = (f32x4){0.f, 0.f, 0.f, 0.f};
        s0 = __builtin_amdgcn_mfma_f32_16x16x32_bf16(kA, qf0, s0, 0, 0, 0);
        s0 = __builtin_amdgcn_mfma_f32_16x16x32_bf16(kB, qf1, s0, 0, 0, 0);
        f32x4 s1 = (f32x4){0.f, 0.f, 0.f, 0.f};
        s1 = __builtin_amdgcn_mfma_f32_16x16x32_bf16(kC, qf0, s1, 0, 0, 0);
        s1 = __builtin_amdgcn_mfma_f32_16x16x32_bf16(kD, qf1, s1, 0, 0, 0);
        lsum += eterm(s0[0], ca0.x, cs, gl2, sh2);
        lsum += eterm(s0[1], ca0.y, cs, gl2, sh2);
        lsum += eterm(s0[2], ca0.z, cs, gl2, sh2);
        lsum += eterm(s0[3], ca0.w, cs, gl2, sh2);
        lsum += eterm(s1[0], ca1.x, cs, gl2, sh2);
        lsum += eterm(s1[1], ca1.y, cs, gl2, sh2);
        lsum += eterm(s1[2], ca1.z, cs, gl2, sh2);
        lsum += eterm(s1[3], ca1.w, cs, gl2, sh2);
        kA = nA; kB = nB; kC = nC; kD = nD;
      }
      __syncthreads();
    }
  }
  lsum += __shfl_xor(lsum, 16);
  lsum += __shfl_xor(lsum, 32);
  float inv = 1.0f / lsum;

  // ================= pass B ================================================
  f32x4 oacc[4];
  #pragma unroll
  for (int j = 0; j < 4; j++) oacc[j] = (f32x4){0.f, 0.f, 0.f, 0.f};

  {
    const short* kp0 = Kb + (size_t)lr * 64 + (lg << 3);
    short8 kA = *(const short8*)(kp0);
    short8 kB = *(const short8*)(kp0 + 32);
    short8 kC = *(const short8*)(kp0 + 1024);
    short8 kD = *(const short8*)(kp0 + 1024 + 32);
    for (int kc = 0; kc < 2048; kc += 256) {
      float4 mg0 = *(const float4*)(msrc + kc);
      float4 mg1 = *(const float4*)(msrc + kc + 4);
      *(float4*)mdst = mg0;
      *(float4*)(mdst + 4) = mg1;
      __syncthreads();
      #pragma unroll
      for (int mi = 0; mi < 8; ++mi) {
        int cc = mi << 5;
        int c = kc + cc;
        int cn = (c + 32) & 2047;
        const short* kpn = Kb + (size_t)(cn + lr) * 64 + (lg << 3);
        short8 nA = *(const short8*)(kpn);
        short8 nB = *(const short8*)(kpn + 32);
        short8 nC = *(const short8*)(kpn + 1024);
        short8 nD = *(const short8*)(kpn + 1024 + 32);
        const short* vp = Vb + (size_t)lr * 2048 + c + (lg << 3);
        short8 v0 = *(const short8*)(vp);
        short8 v1 = *(const short8*)(vp + 16 * 2048);
        short8 v2 = *(const short8*)(vp + 32 * 2048);
        short8 v3 = *(const short8*)(vp + 48 * 2048);
        int u = (((cc >> 3) + lg) ^ sw) << 3;
        float4 ca0 = *(const float4*)(mrd + u);
        float4 ca1 = *(const float4*)(mrd + u + 4);
        f32x4 s0 = (f32x4){0.f, 0.f, 0.f, 0.f};
        s0 = __builtin_amdgcn_mfma_f32_16x16x32_bf16(kA, qf0, s0, 0, 0, 0);
        s0 = __builtin_amdgcn_mfma_f32_16x16x32_bf16(kB, qf1, s0, 0, 0, 0);
        f32x4 s1 = (f32x4){0.f, 0.f, 0.f, 0.f};
        s1 = __builtin_amdgcn_mfma_f32_16x16x32_bf16(kC, qf0, s1, 0, 0, 0);
        s1 = __builtin_amdgcn_mfma_f32_16x16x32_bf16(kD, qf1, s1, 0, 0, 0);
        float p00 = eterm(s0[0], ca0.x, cs, gl2, sh2) * inv;
        float p01 = eterm(s0[1], ca0.y, cs, gl2, sh2) * inv;
        float p02 = eterm(s0[2], ca0.z, cs, gl2, sh2) * inv;
        float p03 = eterm(s0[3], ca0.w, cs, gl2, sh2) * inv;
        float p10 = eterm(s1[0], ca1.x, cs, gl2, sh2) * inv;
        float p11 = eterm(s1[1], ca1.y, cs, gl2, sh2) * inv;
        float p12 = eterm(s1[2], ca1.z, cs, gl2, sh2) * inv;
        float p13 = eterm(s1[3], ca1.w, cs, gl2, sh2) * inv;
        union { unsigned u4[4]; short8 s8; uint4 q4; } pu;
        pu.u4[0] = pk2(p00, p01);
        pu.u4[1] = pk2(p02, p03);
        pu.u4[2] = pk2(p10, p11);
        pu.u4[3] = pk2(p12, p13);
        {
          int c16 = (cc >> 3) + lg;           // 16B unit within [0,32)
          *(uint4*)&P_lds[w][lr][(c16 ^ sw) << 3] = pu.q4;
        }
        oacc[0] = __builtin_amdgcn_mfma_f32_16x16x32_bf16(pu.s8, v0, oacc[0], 0, 0, 0);
        oacc[1] = __builtin_amdgcn_mfma_f32_16x16x32_bf16(pu.s8, v1, oacc[1], 0, 0, 0);
        oacc[2] = __builtin_amdgcn_mfma_f32_16x16x32_bf16(pu.s8, v2, oacc[2], 0, 0, 0);
        oacc[3] = __builtin_amdgcn_mfma_f32_16x16x32_bf16(pu.s8, v3, oacc[3], 0, 0, 0);
        kA = nA; kB = nB; kC = nC; kD = nD;
      }
      // flush this wave's 16x256 P tile as 1KB-contiguous row bursts
      asm volatile("s_waitcnt lgkmcnt(0)" ::: "memory");
      __builtin_amdgcn_sched_barrier(0);
      #pragma unroll
      for (int r = 0; r < 16; ++r) {
        const unsigned* pr = (const unsigned*)&P_lds[w][r]
            [(((lane >> 1) ^ (r & 7)) << 3) + ((lane & 1) << 2)];
        uint2 pv = *(const uint2*)pr;
        float4 o;
        o.x = bfu2f(pv.x & 0xFFFFu);
        o.y = bfu2f(pv.x >> 16);
        o.z = bfu2f(pv.y & 0xFFFFu);
        o.w = bfu2f(pv.y >> 16);
        *(float4*)(Ab + (size_t)(q0 + r) * 2048 + kc + (lane << 2)) = o;
      }
      __syncthreads();
    }
  }

  int h = w;
  #pragma unroll
  for (int j = 0; j < 4; j++)
    #pragma unroll
    for (int r = 0; r < 4; r++) {
      int qq = q0 + (lg << 2) + r;
      out[((size_t)(bb * 2048) + qq) * 512 + (h << 6) + (j << 4) + lr] = oacc[j][r];
    }
}

extern "C" void kernel_launch(void* const* d_in, const int* in_sizes, int n_in,
                              void* d_out, int out_size, void* d_ws, size_t ws_size,
                              hipStream_t stream) {
  const float* q    = (const float*)d_in[0];
  const float* k    = (const float*)d_in[1];
  const float* v    = (const float*)d_in[2];
  const float* mask = (const float*)d_in[3];
  const float* Wq   = (const float*)d_in[4];
  const float* Wk   = (const float*)d_in[5];
  const float* Wv   = (const float*)d_in[6];
  const float* gma  = (const float*)d_in[7];
  float* out = (float*)d_out;
  float* attn_out = out + (size_t)4 * 2048 * 512;

  short* wt = (short*)d_ws;                              // 1.5 MB
  short* qh = (short*)((char*)d_ws + (2u << 20));        // 8 MB
  short* kh = qh + (size_t)4 * 8 * 2048 * 64;            // 8 MB (row-permuted)
  short* vt = kh + (size_t)4 * 8 * 2048 * 64;            // 8 MB
  short* xb = vt + (size_t)4 * 8 * 2048 * 64;            // 24 MB (optional)
  bool big_ws = ws_size >= (size_t)(50u << 20);

  hipLaunchKernelGGL(prep_wt_k, dim3(3072), dim3(256), 0, stream, Wq, Wk, Wv, wt);
  if (big_ws) {
    hipLaunchKernelGGL(xcvt_k, dim3(6144), dim3(256), 0, stream, q, k, v, xb);
    hipLaunchKernelGGL(proj_k<1>, dim3(3072), dim3(64), 0, stream, q, k, v, xb, wt, qh, kh, vt);
  } else {
    hipLaunchKernelGGL(proj_k<0>, dim3(3072), dim3(64), 0, stream, q, k, v, xb, wt, qh, kh, vt);
  }
  hipLaunchKernelGGL(attn_k, dim3(512), dim3(512), 0, stream, qh, kh, vt, mask, gma,
                     out, attn_out);
}

// Round 9
// 527.784 us; speedup vs baseline: 2.0868x; 1.0421x over previous
//
#include <hip/hip_runtime.h>

// B=4, S=2048, D=512, H=8, DK=DV=64
typedef __attribute__((ext_vector_type(8))) short short8;
typedef __attribute__((ext_vector_type(4))) float f32x4;

__device__ __forceinline__ short f2bf(float f) {
  union { float f; unsigned u; } x; x.f = f;
  return (short)((x.u + 0x7FFFu + ((x.u >> 16) & 1u)) >> 16);
}
__device__ __forceinline__ unsigned pk2(float a, float b) {
  return (unsigned)(unsigned short)f2bf(a) | ((unsigned)(unsigned short)f2bf(b) << 16);
}
__device__ __forceinline__ float bfu2f(unsigned lo16) {
  union { unsigned u; float f; } x; x.u = lo16 << 16; return x.f;
}

// Wt[m][n][k] = W_m[k][n], bf16  (3 x 512 x 512)
__global__ __launch_bounds__(256) void prep_wt_k(const float* __restrict__ Wq,
    const float* __restrict__ Wk, const float* __restrict__ Wv,
    short* __restrict__ wt) {
  int idx = blockIdx.x * 256 + threadIdx.x;
  int m = idx >> 18;
  int r = idx & 0x3FFFF;
  int k = r >> 9, n = r & 511;
  const float* W = (m == 0) ? Wq : (m == 1) ? Wk : Wv;
  wt[(m << 18) + (n << 9) + k] = f2bf(W[(k << 9) + n]);
}

// convert q,k,v f32 -> bf16 [3][8192][512]
__global__ __launch_bounds__(256) void xcvt_k(const float* __restrict__ q,
    const float* __restrict__ k_, const float* __restrict__ v,
    short* __restrict__ xb) {
  int i = blockIdx.x * 256 + threadIdx.x;
  int m = i >> 19;
  int r = i & 0x7FFFF;
  const float* X = (m == 0) ? q : (m == 1) ? k_ : v;
  float4 f0 = ((const float4*)X)[2 * r];
  float4 f1 = ((const float4*)X)[2 * r + 1];
  short8 t;
  t[0] = f2bf(f0.x); t[1] = f2bf(f0.y); t[2] = f2bf(f0.z); t[3] = f2bf(f0.w);
  t[4] = f2bf(f1.x); t[5] = f2bf(f1.y); t[6] = f2bf(f1.z); t[7] = f2bf(f1.w);
  *(short8*)(xb + (size_t)i * 8) = t;
}

// X[8192][512] @ Wt[n][k] -> qh [b][h][s][64], kh row-permuted, vt [b][h][dv][s]
template<int BF>
__global__ __launch_bounds__(64) void proj_k(const float* __restrict__ q,
    const float* __restrict__ k_, const float* __restrict__ v,
    const short* __restrict__ xb, const short* __restrict__ wt,
    short* __restrict__ qh, short* __restrict__ kh, short* __restrict__ vt) {
  int bid = blockIdx.x;
  int mat = bid >> 10;
  int t = bid & 1023;
  int tm = t >> 3, tn = t & 7;
  const float* X = (mat == 0) ? q : (mat == 1) ? k_ : v;
  const short* Xb = xb + ((size_t)mat << 22);
  const short* W = wt + ((size_t)mat << 18);
  int lane = threadIdx.x;
  int lr = lane & 15, lg = lane >> 4;
  int m0 = tm << 6, n0 = tn << 6;
  f32x4 acc[4][4];
  #pragma unroll
  for (int i = 0; i < 4; i++)
    #pragma unroll
    for (int j = 0; j < 4; j++) acc[i][j] = (f32x4){0.f, 0.f, 0.f, 0.f};
  for (int k0 = 0; k0 < 512; k0 += 32) {
    short8 a[4], bfr[4];
    #pragma unroll
    for (int i = 0; i < 4; i++) {
      if (BF) {
        a[i] = *(const short8*)(Xb + (size_t)(m0 + 16 * i + lr) * 512 + k0 + 8 * lg);
      } else {
        const float* p = X + (size_t)(m0 + 16 * i + lr) * 512 + k0 + 8 * lg;
        float4 f0 = *(const float4*)p;
        float4 f1 = *(const float4*)(p + 4);
        short8 tt;
        tt[0] = f2bf(f0.x); tt[1] = f2bf(f0.y); tt[2] = f2bf(f0.z); tt[3] = f2bf(f0.w);
        tt[4] = f2bf(f1.x); tt[5] = f2bf(f1.y); tt[6] = f2bf(f1.z); tt[7] = f2bf(f1.w);
        a[i] = tt;
      }
    }
    #pragma unroll
    for (int j = 0; j < 4; j++)
      bfr[j] = *(const short8*)(W + (size_t)(n0 + 16 * j + lr) * 512 + k0 + 8 * lg);
    #pragma unroll
    for (int i = 0; i < 4; i++)
      #pragma unroll
      for (int j = 0; j < 4; j++)
        acc[i][j] = __builtin_amdgcn_mfma_f32_16x16x32_bf16(a[i], bfr[j], acc[i][j], 0, 0, 0);
  }
  #pragma unroll
  for (int i = 0; i < 4; i++)
    #pragma unroll
    for (int j = 0; j < 4; j++)
      #pragma unroll
      for (int r = 0; r < 4; r++) {
        int row = m0 + 16 * i + lg * 4 + r;
        int col = n0 + 16 * j + lr;
        int bb = row >> 11, s = row & 2047;
        int h = col >> 6, d = col & 63;
        short val = f2bf(acc[i][j][r]);
        if (mat == 0) {
          qh[((size_t)((bb * 8 + h) * 2048 + s) << 6) + d] = val;
        } else if (mat == 1) {
          int o = s & 31, aa = o >> 3, b7 = o & 7;
          int loc = (b7 < 4) ? ((aa << 2) | b7) : (16 + ((aa << 2) | (b7 - 4)));
          int sp = (s & ~31) | loc;
          kh[((size_t)((bb * 8 + h) * 2048 + sp) << 6) + d] = val;
        } else {
          vt[((size_t)((bb * 8 + h) * 64 + d) << 11) + s] = val;
        }
      }
}

__device__ __forceinline__ float eterm(float s, float m, float cs, float gl2, float sh2) {
  return __builtin_amdgcn_exp2f(fmaf(s, cs, fmaf(m, gl2, -sh2)));
}

// Block = (batch, 16 q-rows) x 8 heads (wave = head). Mask staged once in LDS.
// LDS cut to 32 KB (P flushed every 64 cols) -> 2 blocks/CU, 4 waves/SIMD.
__global__ __launch_bounds__(512, 4) void attn_k(const short* __restrict__ qh,
    const short* __restrict__ kh, const short* __restrict__ vt,
    const float* __restrict__ mask, const float* __restrict__ gamma_p,
    float* __restrict__ out, float* __restrict__ attn_out) {
  __shared__ __align__(16) short P_lds[8][16][64];    // 16 KB (per-wave 64-col P tiles)
  __shared__ __align__(16) float M_lds[16][256];      // 16 KB (shared mask tile)

  int bid = blockIdx.x;
  int bb = bid >> 7;
  int q0 = (bid & 127) << 4;
  int w = threadIdx.x >> 6;
  int lane = threadIdx.x & 63;
  int lr = lane & 15, lg = lane >> 4;
  int bh = bb * 8 + w;
  const short* Kb = kh + (size_t)bh * (2048 * 64);
  const short* Qb = qh + (size_t)bh * (2048 * 64);
  const short* Vb = vt + (size_t)bh * (64 * 2048);
  const float* Mb = mask + (size_t)bb * (2048 * 2048);
  float* Ab = attn_out + (size_t)bh * (2048 * 2048);
  const float LOG2E = 1.4426950408889634f;
  float gamma = gamma_p[0];
  float shift = fmaxf(gamma, 0.f) + 16.0f;
  float cs = 0.125f * LOG2E;
  float gl2 = gamma * LOG2E;
  float sh2 = shift * LOG2E;

  int srow = threadIdx.x >> 5;
  int sc8 = threadIdx.x & 31;
  const float* msrc = Mb + (size_t)(q0 + srow) * 2048 + (sc8 << 3);
  float* mdst = &M_lds[srow][((sc8 ^ (srow & 7)) << 3)];

  short8 qf0 = *(const short8*)(Qb + (size_t)(q0 + lr) * 64 + 8 * lg);
  short8 qf1 = *(const short8*)(Qb + (size_t)(q0 + lr) * 64 + 32 + 8 * lg);
  const float* mrd = &M_lds[lr][0];
  int sw = lr & 7;

  // ================= pass A: row sums =================
  float lsum = 0.f;
  for (int kc = 0; kc < 2048; kc += 256) {
    float4 mg0 = *(const float4*)(msrc + kc);
    float4 mg1 = *(const float4*)(msrc + kc + 4);
    *(float4*)mdst = mg0;
    *(float4*)(mdst + 4) = mg1;
    __syncthreads();
    #pragma unroll
    for (int mi = 0; mi < 8; ++mi) {
      int cc = mi << 5;
      const short* kp = Kb + (size_t)(kc + cc + lr) * 64 + (lg << 3);
      short8 kA = *(const short8*)(kp);
      short8 kB = *(const short8*)(kp + 32);
      short8 kC = *(const short8*)(kp + 1024);
      short8 kD = *(const short8*)(kp + 1024 + 32);
      int u = (((cc >> 3) + lg) ^ sw) << 3;
      float4 ca0 = *(const float4*)(mrd + u);
      float4 ca1 = *(const float4*)(mrd + u + 4);
      f32x4 s0 = (f32x4){0.f, 0.f, 0.f, 0.f};
      s0 = __builtin_amdgcn_mfma_f32_16x16x32_bf16(kA, qf0, s0, 0, 0, 0);
      s0 = __builtin_amdgcn_mfma_f32_16x16x32_bf16(kB, qf1, s0, 0, 0, 0);
      f32x4 s1 = (f32x4){0.f, 0.f, 0.f, 0.f};
      s1 = __builtin_amdgcn_mfma_f32_16x16x32_bf16(kC, qf0, s1, 0, 0, 0);
      s1 = __builtin_amdgcn_mfma_f32_16x16x32_bf16(kD, qf1, s1, 0, 0, 0);
      lsum += eterm(s0[0], ca0.x, cs, gl2, sh2);
      lsum += eterm(s0[1], ca0.y, cs, gl2, sh2);
      lsum += eterm(s0[2], ca0.z, cs, gl2, sh2);
      lsum += eterm(s0[3], ca0.w, cs, gl2, sh2);
      lsum += eterm(s1[0], ca1.x, cs, gl2, sh2);
      lsum += eterm(s1[1], ca1.y, cs, gl2, sh2);
      lsum += eterm(s1[2], ca1.z, cs, gl2, sh2);
      lsum += eterm(s1[3], ca1.w, cs, gl2, sh2);
    }
    __syncthreads();
  }
  lsum += __shfl_xor(lsum, 16);
  lsum += __shfl_xor(lsum, 32);
  float inv = 1.0f / lsum;

  // ================= pass B =================
  f32x4 oacc[4];
  #pragma unroll
  for (int j = 0; j < 4; j++) oacc[j] = (f32x4){0.f, 0.f, 0.f, 0.f};

  for (int kc = 0; kc < 2048; kc += 256) {
    float4 mg0 = *(const float4*)(msrc + kc);
    float4 mg1 = *(const float4*)(msrc + kc + 4);
    *(float4*)mdst = mg0;
    *(float4*)(mdst + 4) = mg1;
    __syncthreads();
    #pragma unroll
    for (int mi = 0; mi < 8; ++mi) {
      int cc = mi << 5;
      int c = kc + cc;
      const short* kp = Kb + (size_t)(c + lr) * 64 + (lg << 3);
      short8 kA = *(const short8*)(kp);
      short8 kB = *(const short8*)(kp + 32);
      short8 kC = *(const short8*)(kp + 1024);
      short8 kD = *(const short8*)(kp + 1024 + 32);
      const short* vp = Vb + (size_t)lr * 2048 + c + (lg << 3);
      short8 v0 = *(const short8*)(vp);
      short8 v1 = *(const short8*)(vp + 16 * 2048);
      short8 v2 = *(const short8*)(vp + 32 * 2048);
      short8 v3 = *(const short8*)(vp + 48 * 2048);
      int u = (((cc >> 3) + lg) ^ sw) << 3;
      float4 ca0 = *(const float4*)(mrd + u);
      float4 ca1 = *(const float4*)(mrd + u + 4);
      f32x4 s0 = (f32x4){0.f, 0.f, 0.f, 0.f};
      s0 = __builtin_amdgcn_mfma_f32_16x16x32_bf16(kA, qf0, s0, 0, 0, 0);
      s0 = __builtin_amdgcn_mfma_f32_16x16x32_bf16(kB, qf1, s0, 0, 0, 0);
      f32x4 s1 = (f32x4){0.f, 0.f, 0.f, 0.f};
      s1 = __builtin_amdgcn_mfma_f32_16x16x32_bf16(kC, qf0, s1, 0, 0, 0);
      s1 = __builtin_amdgcn_mfma_f32_16x16x32_bf16(kD, qf1, s1, 0, 0, 0);
      float p00 = eterm(s0[0], ca0.x, cs, gl2, sh2) * inv;
      float p01 = eterm(s0[1], ca0.y, cs, gl2, sh2) * inv;
      float p02 = eterm(s0[2], ca0.z, cs, gl2, sh2) * inv;
      float p03 = eterm(s0[3], ca0.w, cs, gl2, sh2) * inv;
      float p10 = eterm(s1[0], ca1.x, cs, gl2, sh2) * inv;
      float p11 = eterm(s1[1], ca1.y, cs, gl2, sh2) * inv;
      float p12 = eterm(s1[2], ca1.z, cs, gl2, sh2) * inv;
      float p13 = eterm(s1[3], ca1.w, cs, gl2, sh2) * inv;
      union { unsigned u4[4]; short8 s8; uint4 q4; } pu;
      pu.u4[0] = pk2(p00, p01);
      pu.u4[1] = pk2(p02, p03);
      pu.u4[2] = pk2(p10, p11);
      pu.u4[3] = pk2(p12, p13);
      {
        int c16 = ((mi & 1) << 2) + lg;      // 16B unit within 64-col buffer [0,8)
        *(uint4*)&P_lds[w][lr][(c16 ^ sw) << 3] = pu.q4;
      }
      oacc[0] = __builtin_amdgcn_mfma_f32_16x16x32_bf16(pu.s8, v0, oacc[0], 0, 0, 0);
      oacc[1] = __builtin_amdgcn_mfma_f32_16x16x32_bf16(pu.s8, v1, oacc[1], 0, 0, 0);
      oacc[2] = __builtin_amdgcn_mfma_f32_16x16x32_bf16(pu.s8, v2, oacc[2], 0, 0, 0);
      oacc[3] = __builtin_amdgcn_mfma_f32_16x16x32_bf16(pu.s8, v3, oacc[3], 0, 0, 0);

      if (mi & 1) {
        // flush this wave's 16x64 P tile (wave-private; no block sync needed)
        int cbase = kc + ((mi >> 1) << 6);
        asm volatile("s_waitcnt lgkmcnt(0)" ::: "memory");
        __builtin_amdgcn_sched_barrier(0);
        int fr = lane >> 3;                  // 0..7
        int c8 = lane & 7;                   // 16B unit within row
        #pragma unroll
        for (int p = 0; p < 2; ++p) {
          int row = fr + (p << 3);
          int unit = c8 ^ (row & 7);
          uint4 pv = *(const uint4*)&P_lds[w][row][unit << 3];
          f32x4 lo = (f32x4){bfu2f(pv.x & 0xFFFFu), bfu2f(pv.x >> 16),
                             bfu2f(pv.y & 0xFFFFu), bfu2f(pv.y >> 16)};
          f32x4 hi = (f32x4){bfu2f(pv.z & 0xFFFFu), bfu2f(pv.z >> 16),
                             bfu2f(pv.w & 0xFFFFu), bfu2f(pv.w >> 16)};
          float* dst = Ab + (size_t)(q0 + row) * 2048 + cbase + (c8 << 3);
          *(f32x4*)dst = lo;
          *(f32x4*)(dst + 4) = hi;
        }
      }
    }
    __syncthreads();
  }

  int h = w;
  #pragma unroll
  for (int j = 0; j < 4; j++)
    #pragma unroll
    for (int r = 0; r < 4; r++) {
      int qq = q0 + (lg << 2) + r;
      out[((size_t)(bb * 2048) + qq) * 512 + (h << 6) + (j << 4) + lr] = oacc[j][r];
    }
}

extern "C" void kernel_launch(void* const* d_in, const int* in_sizes, int n_in,
                              void* d_out, int out_size, void* d_ws, size_t ws_size,
                              hipStream_t stream) {
  const float* q    = (const float*)d_in[0];
  const float* k    = (const float*)d_in[1];
  const float* v    = (const float*)d_in[2];
  const float* mask = (const float*)d_in[3];
  const float* Wq   = (const float*)d_in[4];
  const float* Wk   = (const float*)d_in[5];
  const float* Wv   = (const float*)d_in[6];
  const float* gma  = (const float*)d_in[7];
  float* out = (float*)d_out;
  float* attn_out = out + (size_t)4 * 2048 * 512;

  short* wt = (short*)d_ws;                              // 1.5 MB
  short* qh = (short*)((char*)d_ws + (2u << 20));        // 8 MB
  short* kh = qh + (size_t)4 * 8 * 2048 * 64;            // 8 MB (row-permuted)
  short* vt = kh + (size_t)4 * 8 * 2048 * 64;            // 8 MB
  short* xb = vt + (size_t)4 * 8 * 2048 * 64;            // 24 MB (optional)
  bool big_ws = ws_size >= (size_t)(50u << 20);

  hipLaunchKernelGGL(prep_wt_k, dim3(3072), dim3(256), 0, stream, Wq, Wk, Wv, wt);
  if (big_ws) {
    hipLaunchKernelGGL(xcvt_k, dim3(6144), dim3(256), 0, stream, q, k, v, xb);
    hipLaunchKernelGGL(proj_k<1>, dim3(3072), dim3(64), 0, stream, q, k, v, xb, wt, qh, kh, vt);
  } else {
    hipLaunchKernelGGL(proj_k<0>, dim3(3072), dim3(64), 0, stream, q, k, v, xb, wt, qh, kh, vt);
  }
  hipLaunchKernelGGL(attn_k, dim3(512), dim3(512), 0, stream, qh, kh, vt, mask, gma,
                     out, attn_out);
}

// Round 11
// 346.248 us; speedup vs baseline: 3.1810x; 1.5243x over previous
//
#include <hip/hip_runtime.h>

// B=4, S=2048, D=512, H=8, DK=DV=64
typedef __attribute__((ext_vector_type(8))) short short8;
typedef __attribute__((ext_vector_type(4))) float f32x4;

__device__ __forceinline__ short f2bf(float f) {
  union { float f; unsigned u; } x; x.f = f;
  return (short)((x.u + 0x7FFFu + ((x.u >> 16) & 1u)) >> 16);
}
__device__ __forceinline__ unsigned pk2(float a, float b) {
  return (unsigned)(unsigned short)f2bf(a) | ((unsigned)(unsigned short)f2bf(b) << 16);
}
__device__ __forceinline__ float bfu2f(unsigned lo16) {
  union { unsigned u; float f; } x; x.u = lo16 << 16; return x.f;
}

// Wt[m][n][k] = W_m[k][n], bf16  (3 x 512 x 512)
__global__ __launch_bounds__(256) void prep_wt_k(const float* __restrict__ Wq,
    const float* __restrict__ Wk, const float* __restrict__ Wv,
    short* __restrict__ wt) {
  int idx = blockIdx.x * 256 + threadIdx.x;
  int m = idx >> 18;
  int r = idx & 0x3FFFF;
  int k = r >> 9, n = r & 511;
  const float* W = (m == 0) ? Wq : (m == 1) ? Wk : Wv;
  wt[(m << 18) + (n << 9) + k] = f2bf(W[(k << 9) + n]);
}

// convert q,k,v f32 -> bf16 [3][8192][512]
__global__ __launch_bounds__(256) void xcvt_k(const float* __restrict__ q,
    const float* __restrict__ k_, const float* __restrict__ v,
    short* __restrict__ xb) {
  int i = blockIdx.x * 256 + threadIdx.x;
  int m = i >> 19;
  int r = i & 0x7FFFF;
  const float* X = (m == 0) ? q : (m == 1) ? k_ : v;
  float4 f0 = ((const float4*)X)[2 * r];
  float4 f1 = ((const float4*)X)[2 * r + 1];
  short8 t;
  t[0] = f2bf(f0.x); t[1] = f2bf(f0.y); t[2] = f2bf(f0.z); t[3] = f2bf(f0.w);
  t[4] = f2bf(f1.x); t[5] = f2bf(f1.y); t[6] = f2bf(f1.z); t[7] = f2bf(f1.w);
  *(short8*)(xb + (size_t)i * 8) = t;
}

// X[8192][512] @ Wt[n][k] -> qh [b][h][s][64], kh row-permuted, vt [b][h][dv][s]
template<int BF>
__global__ __launch_bounds__(64) void proj_k(const float* __restrict__ q,
    const float* __restrict__ k_, const float* __restrict__ v,
    const short* __restrict__ xb, const short* __restrict__ wt,
    short* __restrict__ qh, short* __restrict__ kh, short* __restrict__ vt) {
  int bid = blockIdx.x;
  int mat = bid >> 10;
  int t = bid & 1023;
  int tm = t >> 3, tn = t & 7;
  const float* X = (mat == 0) ? q : (mat == 1) ? k_ : v;
  const short* Xb = xb + ((size_t)mat << 22);
  const short* W = wt + ((size_t)mat << 18);
  int lane = threadIdx.x;
  int lr = lane & 15, lg = lane >> 4;
  int m0 = tm << 6, n0 = tn << 6;
  f32x4 acc[4][4];
  #pragma unroll
  for (int i = 0; i < 4; i++)
    #pragma unroll
    for (int j = 0; j < 4; j++) acc[i][j] = (f32x4){0.f, 0.f, 0.f, 0.f};
  for (int k0 = 0; k0 < 512; k0 += 32) {
    short8 a[4], bfr[4];
    #pragma unroll
    for (int i = 0; i < 4; i++) {
      if (BF) {
        a[i] = *(const short8*)(Xb + (size_t)(m0 + 16 * i + lr) * 512 + k0 + 8 * lg);
      } else {
        const float* p = X + (size_t)(m0 + 16 * i + lr) * 512 + k0 + 8 * lg;
        float4 f0 = *(const float4*)p;
        float4 f1 = *(const float4*)(p + 4);
        short8 tt;
        tt[0] = f2bf(f0.x); tt[1] = f2bf(f0.y); tt[2] = f2bf(f0.z); tt[3] = f2bf(f0.w);
        tt[4] = f2bf(f1.x); tt[5] = f2bf(f1.y); tt[6] = f2bf(f1.z); tt[7] = f2bf(f1.w);
        a[i] = tt;
      }
    }
    #pragma unroll
    for (int j = 0; j < 4; j++)
      bfr[j] = *(const short8*)(W + (size_t)(n0 + 16 * j + lr) * 512 + k0 + 8 * lg);
    #pragma unroll
    for (int i = 0; i < 4; i++)
      #pragma unroll
      for (int j = 0; j < 4; j++)
        acc[i][j] = __builtin_amdgcn_mfma_f32_16x16x32_bf16(a[i], bfr[j], acc[i][j], 0, 0, 0);
  }
  #pragma unroll
  for (int i = 0; i < 4; i++)
    #pragma unroll
    for (int j = 0; j < 4; j++)
      #pragma unroll
      for (int r = 0; r < 4; r++) {
        int row = m0 + 16 * i + lg * 4 + r;
        int col = n0 + 16 * j + lr;
        int bb = row >> 11, s = row & 2047;
        int h = col >> 6, d = col & 63;
        short val = f2bf(acc[i][j][r]);
        if (mat == 0) {
          qh[((size_t)((bb * 8 + h) * 2048 + s) << 6) + d] = val;
        } else if (mat == 1) {
          int o = s & 31, aa = o >> 3, b7 = o & 7;
          int loc = (b7 < 4) ? ((aa << 2) | b7) : (16 + ((aa << 2) | (b7 - 4)));
          int sp = (s & ~31) | loc;
          kh[((size_t)((bb * 8 + h) * 2048 + sp) << 6) + d] = val;
        } else {
          vt[((size_t)((bb * 8 + h) * 64 + d) << 11) + s] = val;
        }
      }
}

__device__ __forceinline__ float eterm(float s, float m, float cs, float gl2, float sh2) {
  return __builtin_amdgcn_exp2f(fmaf(s, cs, fmaf(m, gl2, -sh2)));
}

// Block = one (b,h) x 128 q-rows (8 waves x 16 rows). K/V staged per 64-col tile
// into LDS (XOR-swizzled), double-buffered; shared by all 8 waves.
// XCD-swizzled work id keeps each head's 16 q-blocks on one XCD (L2 locality).
__global__ __launch_bounds__(512, 4) void attn_k(const short* __restrict__ qh,
    const short* __restrict__ kh, const short* __restrict__ vt,
    const float* __restrict__ mask, const float* __restrict__ gamma_p,
    float* __restrict__ out, float* __restrict__ attn_out) {
  __shared__ __align__(16) short Kl[2][4096];        // 2 x 8 KB
  __shared__ __align__(16) short Vl[2][4096];        // 2 x 8 KB
  __shared__ __align__(16) short P_lds[8][16][64];   // 16 KB

  int bid = blockIdx.x;
  int work = ((bid & 7) << 6) + (bid >> 3);   // XCD-bijective: 8 x 64
  int bh = work >> 4;
  int qt = work & 15;
  int q0 = qt << 7;
  int bb = bh >> 3, h = bh & 7;
  int tid = threadIdx.x;
  int w = tid >> 6, lane = tid & 63, lr = lane & 15, lg = lane >> 4;
  int qw = q0 + (w << 4);
  int qg = qw + lr;

  const short* Kb = kh + (size_t)bh * (2048 * 64);
  const short* Qb = qh + (size_t)bh * (2048 * 64);
  const short* Vb = vt + (size_t)bh * (64 * 2048);
  const float* Mrow = mask + (size_t)bb * (2048 * 2048) + (size_t)qg * 2048 + (lg << 3);
  float* Ah = attn_out + (size_t)bh * (2048 * 2048);

  const float LOG2E = 1.4426950408889634f;
  float gamma = gamma_p[0];
  float shift = fmaxf(gamma, 0.f) + 16.0f;
  float cs = 0.125f * LOG2E;
  float gl2 = gamma * LOG2E;
  float sh2 = shift * LOG2E;

  // staging assignment: thread stages 16B of K tile and 16B of V tile
  int sr = tid >> 3;                         // row 0..63 of tile
  int sb = (tid & 7) << 4;                   // byte 0..112 within 128B row
  int sdst = sr * 64 + (((sb) ^ ((sr & 7) << 4)) >> 1);   // swizzled short idx
  const short* Kg = Kb + (size_t)tid * 8;                 // + t*4096
  const short* Vg = Vb + (size_t)sr * 2048 + ((tid & 7) << 3);  // + t*64

  short8 qf0 = *(const short8*)(Qb + (size_t)qg * 64 + 8 * lg);
  short8 qf1 = *(const short8*)(Qb + (size_t)qg * 64 + 32 + 8 * lg);
  int sw = lr & 7;

  // swizzled LDS read helpers (byte XOR ((row&7)<<4))
  #define LDK(cu, row, boff) (*(const short8*)&Kl[cu][(row) * 64 + ((((boff) ^ (((row) & 7) << 4))) >> 1)])
  #define LDV(cu, row, boff) (*(const short8*)&Vl[cu][(row) * 64 + ((((boff) ^ (((row) & 7) << 4))) >> 1)])

  // ================= pass A: row sums =================
  float lsum = 0.f;
  {
    short8 ck = *(const short8*)(Kg);
    float4 a0 = *(const float4*)(Mrow + 0);
    float4 a1 = *(const float4*)(Mrow + 4);
    float4 a2 = *(const float4*)(Mrow + 32);
    float4 a3 = *(const float4*)(Mrow + 36);
    *(short8*)&Kl[0][sdst] = ck;
    __syncthreads();
    for (int t = 0; t < 32; ++t) {
      int cu = t & 1, nx = cu ^ 1;
      short8 nk;
      if (t < 31) nk = *(const short8*)(Kg + (size_t)(t + 1) * 4096);
      int nc = ((t + 1) << 6) & 2047;
      float4 n0 = *(const float4*)(Mrow + nc);
      float4 n1 = *(const float4*)(Mrow + nc + 4);
      float4 n2 = *(const float4*)(Mrow + nc + 32);
      float4 n3 = *(const float4*)(Mrow + nc + 36);
      #pragma unroll
      for (int m = 0; m < 2; ++m) {
        int rA = (m << 5) + lr, rC = rA + 16;
        short8 kA = LDK(cu, rA, (lg << 4));
        short8 kB = LDK(cu, rA, 64 + (lg << 4));
        short8 kC = LDK(cu, rC, (lg << 4));
        short8 kD = LDK(cu, rC, 64 + (lg << 4));
        f32x4 s0 = (f32x4){0.f, 0.f, 0.f, 0.f};
        s0 = __builtin_amdgcn_mfma_f32_16x16x32_bf16(kA, qf0, s0, 0, 0, 0);
        s0 = __builtin_amdgcn_mfma_f32_16x16x32_bf16(kB, qf1, s0, 0, 0, 0);
        f32x4 s1 = (f32x4){0.f, 0.f, 0.f, 0.f};
        s1 = __builtin_amdgcn_mfma_f32_16x16x32_bf16(kC, qf0, s1, 0, 0, 0);
        s1 = __builtin_amdgcn_mfma_f32_16x16x32_bf16(kD, qf1, s1, 0, 0, 0);
        float4 ca0 = (m == 0) ? a0 : a2;
        float4 ca1 = (m == 0) ? a1 : a3;
        lsum += eterm(s0[0], ca0.x, cs, gl2, sh2);
        lsum += eterm(s0[1], ca0.y, cs, gl2, sh2);
        lsum += eterm(s0[2], ca0.z, cs, gl2, sh2);
        lsum += eterm(s0[3], ca0.w, cs, gl2, sh2);
        lsum += eterm(s1[0], ca1.x, cs, gl2, sh2);
        lsum += eterm(s1[1], ca1.y, cs, gl2, sh2);
        lsum += eterm(s1[2], ca1.z, cs, gl2, sh2);
        lsum += eterm(s1[3], ca1.w, cs, gl2, sh2);
      }
      if (t < 31) *(short8*)&Kl[nx][sdst] = nk;
      __syncthreads();
      a0 = n0; a1 = n1; a2 = n2; a3 = n3;
    }
  }
  lsum += __shfl_xor(lsum, 16);
  lsum += __shfl_xor(lsum, 32);
  float inv = 1.0f / lsum;

  // ================= pass B =================
  f32x4 oacc[4];
  #pragma unroll
  for (int j = 0; j < 4; j++) oacc[j] = (f32x4){0.f, 0.f, 0.f, 0.f};

  {
    short8 ck = *(const short8*)(Kg);
    short8 cv = *(const short8*)(Vg);
    float4 a0 = *(const float4*)(Mrow + 0);
    float4 a1 = *(const float4*)(Mrow + 4);
    float4 a2 = *(const float4*)(Mrow + 32);
    float4 a3 = *(const float4*)(Mrow + 36);
    *(short8*)&Kl[0][sdst] = ck;
    *(short8*)&Vl[0][sdst] = cv;
    __syncthreads();
    for (int t = 0; t < 32; ++t) {
      int cu = t & 1, nx = cu ^ 1;
      short8 nk, nv;
      if (t < 31) {
        nk = *(const short8*)(Kg + (size_t)(t + 1) * 4096);
        nv = *(const short8*)(Vg + (size_t)(t + 1) * 64);
      }
      int nc = ((t + 1) << 6) & 2047;
      float4 n0 = *(const float4*)(Mrow + nc);
      float4 n1 = *(const float4*)(Mrow + nc + 4);
      float4 n2 = *(const float4*)(Mrow + nc + 32);
      float4 n3 = *(const float4*)(Mrow + nc + 36);
      #pragma unroll
      for (int m = 0; m < 2; ++m) {
        int rA = (m << 5) + lr, rC = rA + 16;
        short8 kA = LDK(cu, rA, (lg << 4));
        short8 kB = LDK(cu, rA, 64 + (lg << 4));
        short8 kC = LDK(cu, rC, (lg << 4));
        short8 kD = LDK(cu, rC, 64 + (lg << 4));
        short8 v0 = LDV(cu, lr,      (m << 6) + (lg << 4));
        short8 v1 = LDV(cu, 16 + lr, (m << 6) + (lg << 4));
        short8 v2 = LDV(cu, 32 + lr, (m << 6) + (lg << 4));
        short8 v3 = LDV(cu, 48 + lr, (m << 6) + (lg << 4));
        f32x4 s0 = (f32x4){0.f, 0.f, 0.f, 0.f};
        s0 = __builtin_amdgcn_mfma_f32_16x16x32_bf16(kA, qf0, s0, 0, 0, 0);
        s0 = __builtin_amdgcn_mfma_f32_16x16x32_bf16(kB, qf1, s0, 0, 0, 0);
        f32x4 s1 = (f32x4){0.f, 0.f, 0.f, 0.f};
        s1 = __builtin_amdgcn_mfma_f32_16x16x32_bf16(kC, qf0, s1, 0, 0, 0);
        s1 = __builtin_amdgcn_mfma_f32_16x16x32_bf16(kD, qf1, s1, 0, 0, 0);
        float4 ca0 = (m == 0) ? a0 : a2;
        float4 ca1 = (m == 0) ? a1 : a3;
        float p00 = eterm(s0[0], ca0.x, cs, gl2, sh2) * inv;
        float p01 = eterm(s0[1], ca0.y, cs, gl2, sh2) * inv;
        float p02 = eterm(s0[2], ca0.z, cs, gl2, sh2) * inv;
        float p03 = eterm(s0[3], ca0.w, cs, gl2, sh2) * inv;
        float p10 = eterm(s1[0], ca1.x, cs, gl2, sh2) * inv;
        float p11 = eterm(s1[1], ca1.y, cs, gl2, sh2) * inv;
        float p12 = eterm(s1[2], ca1.z, cs, gl2, sh2) * inv;
        float p13 = eterm(s1[3], ca1.w, cs, gl2, sh2) * inv;
        union { unsigned u4[4]; short8 s8; uint4 q4; } pu;
        pu.u4[0] = pk2(p00, p01);
        pu.u4[1] = pk2(p02, p03);
        pu.u4[2] = pk2(p10, p11);
        pu.u4[3] = pk2(p12, p13);
        {
          int c16 = (m << 2) + lg;           // 16B unit within 64-col P buf [0,8)
          *(uint4*)&P_lds[w][lr][(c16 ^ sw) << 3] = pu.q4;
        }
        oacc[0] = __builtin_amdgcn_mfma_f32_16x16x32_bf16(pu.s8, v0, oacc[0], 0, 0, 0);
        oacc[1] = __builtin_amdgcn_mfma_f32_16x16x32_bf16(pu.s8, v1, oacc[1], 0, 0, 0);
        oacc[2] = __builtin_amdgcn_mfma_f32_16x16x32_bf16(pu.s8, v2, oacc[2], 0, 0, 0);
        oacc[3] = __builtin_amdgcn_mfma_f32_16x16x32_bf16(pu.s8, v3, oacc[3], 0, 0, 0);
      }
      // flush wave-private 16x64 P tile -> attn (256B bursts per row)
      asm volatile("s_waitcnt lgkmcnt(0)" ::: "memory");
      __builtin_amdgcn_sched_barrier(0);
      {
        int fr = lane >> 3;
        int c8 = lane & 7;
        #pragma unroll
        for (int p = 0; p < 2; ++p) {
          int row = fr + (p << 3);
          int unit = c8 ^ (row & 7);
          uint4 pv = *(const uint4*)&P_lds[w][row][unit << 3];
          f32x4 lo = (f32x4){bfu2f(pv.x & 0xFFFFu), bfu2f(pv.x >> 16),
                             bfu2f(pv.y & 0xFFFFu), bfu2f(pv.y >> 16)};
          f32x4 hi = (f32x4){bfu2f(pv.z & 0xFFFFu), bfu2f(pv.z >> 16),
                             bfu2f(pv.w & 0xFFFFu), bfu2f(pv.w >> 16)};
          float* dst = Ah + (size_t)(qw + row) * 2048 + (t << 6) + (c8 << 3);
          *(f32x4*)dst = lo;
          *(f32x4*)(dst + 4) = hi;
        }
      }
      if (t < 31) {
        *(short8*)&Kl[nx][sdst] = nk;
        *(short8*)&Vl[nx][sdst] = nv;
      }
      __syncthreads();
      a0 = n0; a1 = n1; a2 = n2; a3 = n3;
    }
  }

  #pragma unroll
  for (int j = 0; j < 4; j++)
    #pragma unroll
    for (int r = 0; r < 4; r++) {
      int qq = qw + (lg << 2) + r;
      out[((size_t)(bb * 2048) + qq) * 512 + (h << 6) + (j << 4) + lr] = oacc[j][r];
    }
  #undef LDK
  #undef LDV
}

extern "C" void kernel_launch(void* const* d_in, const int* in_sizes, int n_in,
                              void* d_out, int out_size, void* d_ws, size_t ws_size,
                              hipStream_t stream) {
  const float* q    = (const float*)d_in[0];
  const float* k    = (const float*)d_in[1];
  const float* v    = (const float*)d_in[2];
  const float* mask = (const float*)d_in[3];
  const float* Wq   = (const float*)d_in[4];
  const float* Wk   = (const float*)d_in[5];
  const float* Wv   = (const float*)d_in[6];
  const float* gma  = (const float*)d_in[7];
  float* out = (float*)d_out;
  float* attn_out = out + (size_t)4 * 2048 * 512;

  short* wt = (short*)d_ws;                              // 1.5 MB
  short* qh = (short*)((char*)d_ws + (2u << 20));        // 8 MB
  short* kh = qh + (size_t)4 * 8 * 2048 * 64;            // 8 MB (row-permuted)
  short* vt = kh + (size_t)4 * 8 * 2048 * 64;            // 8 MB
  short* xb = vt + (size_t)4 * 8 * 2048 * 64;            // 24 MB (optional)
  bool big_ws = ws_size >= (size_t)(50u << 20);

  hipLaunchKernelGGL(prep_wt_k, dim3(3072), dim3(256), 0, stream, Wq, Wk, Wv, wt);
  if (big_ws) {
    hipLaunchKernelGGL(xcvt_k, dim3(6144), dim3(256), 0, stream, q, k, v, xb);
    hipLaunchKernelGGL(proj_k<1>, dim3(3072), dim3(64), 0, stream, q, k, v, xb, wt, qh, kh, vt);
  } else {
    hipLaunchKernelGGL(proj_k<0>, dim3(3072), dim3(64), 0, stream, q, k, v, xb, wt, qh, kh, vt);
  }
  hipLaunchKernelGGL(attn_k, dim3(512), dim3(512), 0, stream, qh, kh, vt, mask, gma,
                     out, attn_out);
}